// Round 5
// baseline (343.411 us; speedup 1.0000x reference)
//
#include <hip/hip_runtime.h>
#include <stdint.h>

typedef unsigned short u16;
typedef __bf16 bf16x8 __attribute__((ext_vector_type(8)));
typedef float fx4 __attribute__((ext_vector_type(4)));
typedef float fx16 __attribute__((ext_vector_type(16)));

// ---------------- helpers ----------------

__device__ __forceinline__ u16 f2bf(float f) {
    unsigned int u = __float_as_uint(f);
    u += 0x7fffu + ((u >> 16) & 1u);   // RNE
    return (u16)(u >> 16);
}

__device__ __forceinline__ bf16x8 ld8(const u16* p) {
    return __builtin_bit_cast(bf16x8, *(const int4*)p);
}

// pack two fp32 -> packed bf16 dword (round-half-up)
__device__ __forceinline__ uint32_t pk2bf(float lo, float hi) {
    uint32_t a = __float_as_uint(lo) + 0x8000u;
    uint32_t b = __float_as_uint(hi) + 0x8000u;
    return __builtin_amdgcn_perm(b, a, 0x07060302u);
}

// async global->LDS, 16B per lane: HW writes lds_base + lane*16
typedef __attribute__((address_space(3))) uint32_t lds_u32;
typedef __attribute__((address_space(1))) const uint32_t glb_u32;
__device__ __forceinline__ void glds16(const u16* g, u16* l) {
    __builtin_amdgcn_global_load_lds((glb_u32*)g, (lds_u32*)l, 16, 0, 0);
}

// ---------------- kernel 0b: transpose + cast weights ----------------

__global__ __launch_bounds__(256) void transpose_cast_kernel(const float* __restrict__ in,
                                                             u16* __restrict__ out,
                                                             int NR, int NC) {
    __shared__ float T[64][65];
    int t = threadIdx.x;
    int i0 = blockIdx.y * 64, j0 = blockIdx.x * 64;
    int r = t >> 4, cc = t & 15;
#pragma unroll
    for (int j = 0; j < 4; ++j) {
        int row = r + j * 16;
        float4 v = *(const float4*)(in + (size_t)(i0 + row) * NC + j0 + cc * 4);
        T[row][cc * 4 + 0] = v.x; T[row][cc * 4 + 1] = v.y;
        T[row][cc * 4 + 2] = v.z; T[row][cc * 4 + 3] = v.w;
    }
    __syncthreads();
#pragma unroll
    for (int j = 0; j < 4; ++j) {
        int jr = r + j * 16;
        unsigned int u0 = f2bf(T[cc * 4 + 0][jr]) | ((unsigned int)f2bf(T[cc * 4 + 1][jr]) << 16);
        unsigned int u1 = f2bf(T[cc * 4 + 2][jr]) | ((unsigned int)f2bf(T[cc * 4 + 3][jr]) << 16);
        uint2 u; u.x = u0; u.y = u1;
        *(uint2*)(out + (size_t)(j0 + jr) * NR + i0 + cc * 4) = u;
    }
}

// ---------------- GEMM: C[M,Ncols] = A[M,512] * Bt[Ncols,512]^T ----------------
// MODE 0: A fp32 (x), cast during LDS staging; B staged via global_load_lds.
//         Scatter into fragment-major blobs (see attn kernel).
// MODE 1: A bf16 (Ob); A and B both staged via global_load_lds. -> d_out fp32 + bias

#define QSCALE 0.180336880f   // (1/8) * log2(e): logits in log2 domain

template<int MODE>
__global__ __launch_bounds__(256) void gemm_kernel(const void* __restrict__ Avoid,
                                                   const u16* __restrict__ Bt,
                                                   u16* __restrict__ Qf,
                                                   u16* __restrict__ Kf,
                                                   u16* __restrict__ Vf,
                                                   const float* __restrict__ bias,
                                                   float* __restrict__ Out,
                                                   int Ncols) {
    __shared__ __align__(16) u16 As[128 * 32];
    __shared__ __align__(16) u16 Bs[128 * 32];
    int tid = threadIdx.x;
    int w = tid >> 6, lane = tid & 63;
    int m16 = lane & 15, quad = lane >> 4;
    int ntn = Ncols / 128;
    int bx = blockIdx.x % ntn, by = blockIdx.x / ntn;
    int r0 = by * 128, c0 = bx * 128;
    int wr = w >> 1, wc = w & 1;
    int lrow = lane >> 2, lchk = (lane & 3) * 8;   // glds lane mapping

    fx4 acc[4][4] = {};

    for (int k0 = 0; k0 < 512; k0 += 32) {
        __syncthreads();
#pragma unroll
        for (int j = 0; j < 2; ++j) {
            int rw = j * 64 + w * 16;              // wave-uniform row base
            if (MODE == 0) {
                int L = tid + j * 256;
                int row = L >> 2, c = L & 3;
                const float* af = (const float*)Avoid + (size_t)(r0 + row) * 512 + k0 + c * 8;
                float4 a = *(const float4*)af, b = *(const float4*)(af + 4);
                int4 v;
                v.x = (int)pk2bf(a.x, a.y); v.y = (int)pk2bf(a.z, a.w);
                v.z = (int)pk2bf(b.x, b.y); v.w = (int)pk2bf(b.z, b.w);
                *(int4*)&As[row * 32 + c * 8] = v;
            } else {
                const u16* ab = (const u16*)Avoid;
                glds16(ab + (size_t)(r0 + rw + lrow) * 512 + k0 + lchk, &As[rw * 32]);
            }
            glds16(Bt + (size_t)(c0 + rw + lrow) * 512 + k0 + lchk, &Bs[rw * 32]);
        }
        __syncthreads();
        bf16x8 af[4], bfr[4];
#pragma unroll
        for (int t = 0; t < 4; ++t) {
            af[t]  = ld8(&As[(wr * 64 + t * 16 + m16) * 32 + quad * 8]);
            bfr[t] = ld8(&Bs[(wc * 64 + t * 16 + m16) * 32 + quad * 8]);
        }
#pragma unroll
        for (int mt = 0; mt < 4; ++mt)
#pragma unroll
            for (int nt = 0; nt < 4; ++nt)
                acc[mt][nt] = __builtin_amdgcn_mfma_f32_16x16x32_bf16(af[mt], bfr[nt], acc[mt][nt], 0, 0, 0);
    }

#pragma unroll
    for (int mt = 0; mt < 4; ++mt) {
        int R0 = r0 + wr * 64 + mt * 16 + quad * 4;
#pragma unroll
        for (int nt = 0; nt < 4; ++nt) {
            int C = c0 + wc * 64 + nt * 16 + m16;
            if (MODE == 0) {
                int sec = C >> 9;                 // 0=q 1=k 2=v
                int hd = (C >> 6) & 7, d = C & 63;
                int b = R0 >> 12, n0 = R0 & 4095;
                size_t hb = (size_t)(b * 8 + hd) * 262144;
                if (sec <= 1) {
                    u16* dst = (sec == 0) ? Qf : Kf;
                    float sc = (sec == 0) ? QSCALE : 1.0f;
                    size_t base = hb + (size_t)((n0 >> 5) * 4 + (d >> 4)) * 512
                                + ((d >> 3) & 1) * 256 + (n0 & 31) * 8 + (d & 7);
#pragma unroll
                    for (int r = 0; r < 4; ++r)
                        dst[base + r * 8] = f2bf(acc[mt][nt][r] * sc);
                } else {
                    size_t base = hb + (size_t)((n0 >> 6) * 8 + (d >> 5) * 4 + ((n0 >> 4) & 3)) * 512
                                + ((n0 >> 2) & 1) * 256 + (d & 31) * 8 + ((n0 >> 3) & 1) * 4;
                    unsigned int u0 = f2bf(acc[mt][nt][0]) | ((unsigned int)f2bf(acc[mt][nt][1]) << 16);
                    unsigned int u1 = f2bf(acc[mt][nt][2]) | ((unsigned int)f2bf(acc[mt][nt][3]) << 16);
                    uint2 u; u.x = u0; u.y = u1;
                    *(uint2*)(Vf + base) = u;
                }
            } else {
                float bv = bias[C];
#pragma unroll
                for (int r = 0; r < 4; ++r)
                    Out[(size_t)(R0 + r) * 512 + C] = acc[mt][nt][r] + bv;
            }
        }
    }
}

// ---------------- flash attention: key-split x2, no cross-lane main loop ----------------
// Static-max softmax (p = 2^S) => O^T and l are additive over keys: waves 0-3 take keys
// 0..2047, waves 4-7 take 2048..4095 of the SAME q-tile; combine via one LDS exchange.

__device__ __forceinline__ void attn_iter(bf16x8 (&KC)[2][4], bf16x8 (&KN)[2][4],
                                          const bf16x8 (&qf)[4], const bf16x8& onesA,
                                          const fx16& Z,
                                          fx16& O0, fx16& O1, fx16& Lacc,
                                          const u16* __restrict__ Kh,
                                          const u16* __restrict__ Vh,
                                          int lane, int K0) {
    // V^T A-frags for this 64-key block (consumed after exp/pack)
    bf16x8 vf[2][4];
    {
        const u16* vb = Vh + (size_t)(K0 >> 6) * 4096 + lane * 8;
#pragma unroll
        for (int dt = 0; dt < 2; ++dt)
#pragma unroll
            for (int ch = 0; ch < 4; ++ch)
                vf[dt][ch] = ld8(vb + (dt * 4 + ch) * 512);
    }
    // prefetch next iteration's K frags (wrap within this wave's 2048-key half)
    {
        int kn0 = (K0 + 64) & 2047;
        const u16* kb = Kh + (size_t)(kn0 >> 5) * 2048 + lane * 8;
#pragma unroll
        for (int dc = 0; dc < 4; ++dc) {
            KN[0][dc] = ld8(kb + dc * 512);
            KN[1][dc] = ld8(kb + 2048 + dc * 512);
        }
    }
    // S^T = K Q^T
    fx16 S0 = Z, S1 = Z;
#pragma unroll
    for (int dc = 0; dc < 4; ++dc) {
        S0 = __builtin_amdgcn_mfma_f32_32x32x16_bf16(KC[0][dc], qf[dc], S0, 0, 0, 0);
        S1 = __builtin_amdgcn_mfma_f32_32x32x16_bf16(KC[1][dc], qf[dc], S1, 0, 0, 0);
    }
    // p = 2^S; packed pairs of consecutive C-regs ARE the B-frags (k-slot permuted V)
    uint32_t pk0[8], pk1[8];
#pragma unroll
    for (int i = 0; i < 8; ++i) {
        pk0[i] = pk2bf(__builtin_amdgcn_exp2f(S0[2 * i]), __builtin_amdgcn_exp2f(S0[2 * i + 1]));
        pk1[i] = pk2bf(__builtin_amdgcn_exp2f(S1[2 * i]), __builtin_amdgcn_exp2f(S1[2 * i + 1]));
    }
    // O^T += V^T P^T ; l += 1^T P^T (ones-MFMA row sums)
#pragma unroll
    for (int c = 0; c < 4; ++c) {
        const uint32_t* pk = (c < 2) ? pk0 : pk1;
        int o = (c & 1) * 4;
        int4 bi; bi.x = (int)pk[o]; bi.y = (int)pk[o + 1]; bi.z = (int)pk[o + 2]; bi.w = (int)pk[o + 3];
        bf16x8 bfrag = __builtin_bit_cast(bf16x8, bi);
        O0 = __builtin_amdgcn_mfma_f32_32x32x16_bf16(vf[0][c], bfrag, O0, 0, 0, 0);
        O1 = __builtin_amdgcn_mfma_f32_32x32x16_bf16(vf[1][c], bfrag, O1, 0, 0, 0);
        Lacc = __builtin_amdgcn_mfma_f32_32x32x16_bf16(onesA, bfrag, Lacc, 0, 0, 0);
    }
}

__global__ __launch_bounds__(512, 4) void attn_kernel(const u16* __restrict__ Qf,
                                                      const u16* __restrict__ Kf,
                                                      const u16* __restrict__ Vf,
                                                      u16* __restrict__ Ob) {
    __shared__ __align__(16) u16 Eo[4 * 32 * 68];
    __shared__ float Cmb[4][64][33];     // partial O^T + l from waves 4-7

    int tid = threadIdx.x;
    int wave = tid >> 6, lane = tid & 63;
    int w = wave & 3, half = wave >> 2;
    int q32 = lane & 31, h = lane >> 5;
    // XCD swizzle: all 32 q-blocks of one (b,h) land on one XCD
    int bh = ((blockIdx.x & 7) << 1) | ((blockIdx.x >> 3) & 1);
    int qt = blockIdx.x >> 4;
    int q0 = qt * 128;

    const u16* Qh = Qf + (size_t)bh * 262144;
    const u16* Kh = Kf + (size_t)bh * 262144 + (size_t)half * 131072;
    const u16* Vh = Vf + (size_t)bh * 262144 + (size_t)half * 131072;

    bf16x8 qf[4];
    {
        const u16* qb = Qh + (size_t)(qt * 4 + w) * 2048 + lane * 8;
#pragma unroll
        for (int dc = 0; dc < 4; ++dc)
            qf[dc] = ld8(qb + dc * 512);
    }

    int4 oi; oi.x = oi.y = oi.z = oi.w = 0x3F803F80;           // bf16 ones
    const bf16x8 onesA = __builtin_bit_cast(bf16x8, oi);
    const fx16 Z = {};
    fx16 O0 = {}, O1 = {}, Lacc = {};

    bf16x8 kA[2][4], kB[2][4];
    {
        const u16* kb = Kh + lane * 8;
#pragma unroll
        for (int dc = 0; dc < 4; ++dc) {
            kA[0][dc] = ld8(kb + dc * 512);
            kA[1][dc] = ld8(kb + 2048 + dc * 512);
        }
    }

    for (int k0 = 0; k0 < 2048; k0 += 128) {
        attn_iter(kA, kB, qf, onesA, Z, O0, O1, Lacc, Kh, Vh, lane, k0);
        attn_iter(kB, kA, qf, onesA, Z, O0, O1, Lacc, Kh, Vh, lane, k0 + 64);
    }

    // ---- cross-wave combine (additive partials) ----
    if (half == 1) {
        float* dst = &Cmb[w][lane][0];
#pragma unroll
        for (int r = 0; r < 16; ++r) { dst[r] = O0[r]; dst[16 + r] = O1[r]; }
        dst[32] = Lacc[0];
    }
    __syncthreads();
    if (half == 0) {
        const float* src = &Cmb[w][lane][0];
#pragma unroll
        for (int r = 0; r < 16; ++r) { O0[r] += src[r]; O1[r] += src[16 + r]; }
        float inv = 1.0f / (Lacc[0] + src[32]);

        // epilogue: O^T/l -> wave-local LDS transpose -> coalesced global bf16 store
        int ebase = w * 2176 + q32 * 68;
#pragma unroll
        for (int i = 0; i < 8; ++i) {
            int dbase = 8 * (i >> 1) + (i & 1) * 2 + 4 * h;
            uint32_t p0 = pk2bf(O0[2 * i] * inv, O0[2 * i + 1] * inv);
            uint32_t p1 = pk2bf(O1[2 * i] * inv, O1[2 * i + 1] * inv);
            *(uint32_t*)&Eo[ebase + dbase]      = p0;
            *(uint32_t*)&Eo[ebase + dbase + 32] = p1;
        }
        asm volatile("s_waitcnt lgkmcnt(0)" ::: "memory");   // wave-local LDS ordering
        int row = lane >> 1, halfc = lane & 1;
        int rb = w * 2176 + row * 68 + halfc * 32;
        int b = bh >> 3, hh = bh & 7;
        size_t gb = ((size_t)(b * 4096 + q0 + w * 32 + row)) * 512 + hh * 64 + halfc * 32;
#pragma unroll
        for (int s = 0; s < 4; ++s) {
            uint2 a = *(const uint2*)&Eo[rb + s * 8];
            uint2 c = *(const uint2*)&Eo[rb + s * 8 + 4];
            int4 v; v.x = (int)a.x; v.y = (int)a.y; v.z = (int)c.x; v.w = (int)c.y;
            *(int4*)(Ob + gb + s * 8) = v;
        }
    }
}

// ---------------- launcher ----------------

extern "C" void kernel_launch(void* const* d_in, const int* in_sizes, int n_in,
                              void* d_out, int out_size, void* d_ws, size_t ws_size,
                              hipStream_t stream) {
    const float* x     = (const float*)d_in[0];   // [2,4096,512]
    const float* w_qkv = (const float*)d_in[1];   // [512,1536]
    const float* w_out = (const float*)d_in[2];   // [512,512]
    const float* b_out = (const float*)d_in[3];   // [512]
    float* out = (float*)d_out;                   // [2,4096,512] fp32

    char* ws = (char*)d_ws;
    u16* wqkv_t = (u16*)(ws);                     //  1.5 MB  [1536][512]
    u16* wout_t = (u16*)(ws + 1572864);           //  0.5 MB  [512][512]
    u16* Qfb    = (u16*)(ws + 2097152);           //  8 MB fragment-major (log2-scaled)
    u16* Kfb    = (u16*)(ws + 10485760);          //  8 MB fragment-major
    u16* Vfb    = (u16*)(ws + 18874368);          //  8 MB fragment-major, k-slot permuted
    u16* Ob     = (u16*)(ws + 27262976);          //  8 MB [8192][512]

    transpose_cast_kernel<<<dim3(24, 8), 256, 0, stream>>>(w_qkv, wqkv_t, 512, 1536);
    transpose_cast_kernel<<<dim3(8, 8), 256, 0, stream>>>(w_out, wout_t, 512, 512);
    gemm_kernel<0><<<768, 256, 0, stream>>>(x, wqkv_t, Qfb, Kfb, Vfb, nullptr, nullptr, 1536);
    attn_kernel<<<512, 512, 0, stream>>>(Qfb, Kfb, Vfb, Ob);
    gemm_kernel<1><<<256, 256, 0, stream>>>(Ob, wout_t, nullptr, nullptr, nullptr, b_out, out, 512);
}

// Round 6
// 220.123 us; speedup vs baseline: 1.5601x; 1.5601x over previous
//
#include <hip/hip_runtime.h>
#include <stdint.h>

typedef unsigned short u16;
typedef __bf16 bf16x8 __attribute__((ext_vector_type(8)));
typedef float fx4 __attribute__((ext_vector_type(4)));
typedef float fx16 __attribute__((ext_vector_type(16)));

// ---------------- helpers ----------------

__device__ __forceinline__ u16 f2bf(float f) {
    unsigned int u = __float_as_uint(f);
    u += 0x7fffu + ((u >> 16) & 1u);   // RNE
    return (u16)(u >> 16);
}

__device__ __forceinline__ bf16x8 ld8(const u16* p) {
    return __builtin_bit_cast(bf16x8, *(const int4*)p);
}

// pack two fp32 -> packed bf16 dword (round-half-up)
__device__ __forceinline__ uint32_t pk2bf(float lo, float hi) {
    uint32_t a = __float_as_uint(lo) + 0x8000u;
    uint32_t b = __float_as_uint(hi) + 0x8000u;
    return __builtin_amdgcn_perm(b, a, 0x07060302u);
}

// async global->LDS, 16B per lane: HW writes lds_base + lane*16
typedef __attribute__((address_space(3))) uint32_t lds_u32;
typedef __attribute__((address_space(1))) const uint32_t glb_u32;
__device__ __forceinline__ void glds16(const u16* g, u16* l) {
    __builtin_amdgcn_global_load_lds((glb_u32*)g, (lds_u32*)l, 16, 0, 0);
}

// ---------------- kernel 0: transpose + cast both weight matrices ----------------
// grid (32, 8): bx<24 -> w_qkv [512][1536], else w_out [512][512]

__global__ __launch_bounds__(256) void transpose_cast_kernel(const float* __restrict__ w_qkv,
                                                             u16* __restrict__ wqkv_t,
                                                             const float* __restrict__ w_out,
                                                             u16* __restrict__ wout_t) {
    __shared__ float T[64][65];
    int t = threadIdx.x;
    int bx = blockIdx.x;
    const float* in; u16* out; int NR = 512, NC;
    if (bx < 24) { in = w_qkv; out = wqkv_t; NC = 1536; }
    else         { in = w_out; out = wout_t; NC = 512; bx -= 24; }
    int i0 = blockIdx.y * 64, j0 = bx * 64;
    int r = t >> 4, cc = t & 15;
#pragma unroll
    for (int j = 0; j < 4; ++j) {
        int row = r + j * 16;
        float4 v = *(const float4*)(in + (size_t)(i0 + row) * NC + j0 + cc * 4);
        T[row][cc * 4 + 0] = v.x; T[row][cc * 4 + 1] = v.y;
        T[row][cc * 4 + 2] = v.z; T[row][cc * 4 + 3] = v.w;
    }
    __syncthreads();
#pragma unroll
    for (int j = 0; j < 4; ++j) {
        int jr = r + j * 16;
        unsigned int u0 = f2bf(T[cc * 4 + 0][jr]) | ((unsigned int)f2bf(T[cc * 4 + 1][jr]) << 16);
        unsigned int u1 = f2bf(T[cc * 4 + 2][jr]) | ((unsigned int)f2bf(T[cc * 4 + 3][jr]) << 16);
        uint2 u; u.x = u0; u.y = u1;
        *(uint2*)(out + (size_t)(j0 + jr) * NR + i0 + cc * 4) = u;
    }
}

// ---------------- GEMM: C[M,Ncols] = A[M,512] * Bt[Ncols,512]^T ----------------
// MODE 0: A fp32 (x), cast during LDS staging; B via global_load_lds.
//         Epilogue: restage C-tile in LDS in fragment-blob order, then fully
//         coalesced 1KB-per-wave stores into Qf/Kf/Vf.
// MODE 1: A bf16 (Ob); A and B via global_load_lds. -> d_out fp32 + bias

#define QSCALE 0.180336880f   // (1/8) * log2(e): logits in log2 domain

template<int MODE>
__global__ __launch_bounds__(256) void gemm_kernel(const void* __restrict__ Avoid,
                                                   const u16* __restrict__ Bt,
                                                   u16* __restrict__ Qf,
                                                   u16* __restrict__ Kf,
                                                   u16* __restrict__ Vf,
                                                   const float* __restrict__ bias,
                                                   float* __restrict__ Out,
                                                   int Ncols) {
    __shared__ __align__(16) u16 Sh[16384];        // 32 KB: As=Sh[0..4096), Bs=Sh[4096..8192); epilogue uses all
    int tid = threadIdx.x;
    int w = tid >> 6, lane = tid & 63;
    int m16 = lane & 15, quad = lane >> 4;
    int ntn = Ncols / 128;
    int bx = blockIdx.x % ntn, by = blockIdx.x / ntn;
    int r0 = by * 128, c0 = bx * 128;
    int wr = w >> 1, wc = w & 1;
    int lrow = lane >> 2, lchk = (lane & 3) * 8;   // glds lane mapping

    fx4 acc[4][4] = {};

    for (int k0 = 0; k0 < 512; k0 += 32) {
        __syncthreads();
#pragma unroll
        for (int j = 0; j < 2; ++j) {
            int rw = j * 64 + w * 16;              // wave-uniform row base
            if (MODE == 0) {
                int L = tid + j * 256;
                int row = L >> 2, c = L & 3;
                const float* af = (const float*)Avoid + (size_t)(r0 + row) * 512 + k0 + c * 8;
                float4 a = *(const float4*)af, b = *(const float4*)(af + 4);
                int4 v;
                v.x = (int)pk2bf(a.x, a.y); v.y = (int)pk2bf(a.z, a.w);
                v.z = (int)pk2bf(b.x, b.y); v.w = (int)pk2bf(b.z, b.w);
                *(int4*)&Sh[row * 32 + c * 8] = v;
            } else {
                const u16* ab = (const u16*)Avoid;
                glds16(ab + (size_t)(r0 + rw + lrow) * 512 + k0 + lchk, &Sh[rw * 32]);
            }
            glds16(Bt + (size_t)(c0 + rw + lrow) * 512 + k0 + lchk, &Sh[4096 + rw * 32]);
        }
        __syncthreads();
        bf16x8 af[4], bfr[4];
#pragma unroll
        for (int t = 0; t < 4; ++t) {
            af[t]  = ld8(&Sh[(wr * 64 + t * 16 + m16) * 32 + quad * 8]);
            bfr[t] = ld8(&Sh[4096 + (wc * 64 + t * 16 + m16) * 32 + quad * 8]);
        }
#pragma unroll
        for (int mt = 0; mt < 4; ++mt)
#pragma unroll
            for (int nt = 0; nt < 4; ++nt)
                acc[mt][nt] = __builtin_amdgcn_mfma_f32_16x16x32_bf16(af[mt], bfr[nt], acc[mt][nt], 0, 0, 0);
    }

    if (MODE == 0) {
        // ---- epilogue: C-tile -> LDS in fragment-blob order -> coalesced stores ----
        int sec = c0 >> 9;                         // tile-uniform: 0=q 1=k 2=v
        __syncthreads();                           // all waves done reading Sh
        if (sec <= 1) {
            float sc = (sec == 0) ? QSCALE : 1.0f;
#pragma unroll
            for (int mt = 0; mt < 4; ++mt)
#pragma unroll
                for (int nt = 0; nt < 4; ++nt) {
                    int lb = wc * 16 + (wr * 2 + (mt >> 1)) * 4 + nt;
                    int eb = lb * 512 + (m16 >> 3) * 256 + ((mt & 1) * 16 + quad * 4) * 8 + (m16 & 7);
#pragma unroll
                    for (int r = 0; r < 4; ++r)
                        Sh[eb + r * 8] = f2bf(acc[mt][nt][r] * sc);
                }
        } else {
#pragma unroll
            for (int mt = 0; mt < 4; ++mt)
#pragma unroll
                for (int nt = 0; nt < 4; ++nt) {
                    int lb = wc * 16 + wr * 8 + (nt >> 1) * 4 + mt;
                    int eb = lb * 512 + (quad & 1) * 256 + ((nt & 1) * 16 + m16) * 8 + (quad >> 1) * 4;
                    unsigned int u0 = f2bf(acc[mt][nt][0]) | ((unsigned int)f2bf(acc[mt][nt][1]) << 16);
                    unsigned int u1 = f2bf(acc[mt][nt][2]) | ((unsigned int)f2bf(acc[mt][nt][3]) << 16);
                    uint2 u; u.x = u0; u.y = u1;
                    *(uint2*)&Sh[eb] = u;
                }
        }
        __syncthreads();
        int b_ = r0 >> 12, n0 = r0 & 4095, hd0 = (c0 >> 6) & 7;
        u16* dst; size_t gb0;
        if (sec == 0)      { dst = Qf; gb0 = (size_t)(n0 >> 5) * 2048; }
        else if (sec == 1) { dst = Kf; gb0 = (size_t)(n0 >> 5) * 2048; }
        else               { dst = Vf; gb0 = (size_t)(n0 >> 6) * 4096; }
        int hl = tid >> 7;                         // head within tile
        size_t gbase = (size_t)(b_ * 8 + hd0 + hl) * 262144 + gb0 + (size_t)(tid & 127) * 64;
#pragma unroll
        for (int s = 0; s < 8; ++s)
            *(int4*)(dst + gbase + s * 8) = *(const int4*)&Sh[tid * 64 + s * 8];
    } else {
#pragma unroll
        for (int mt = 0; mt < 4; ++mt) {
            int R0 = r0 + wr * 64 + mt * 16 + quad * 4;
#pragma unroll
            for (int nt = 0; nt < 4; ++nt) {
                int C = c0 + wc * 64 + nt * 16 + m16;
                float bv = bias[C];
#pragma unroll
                for (int r = 0; r < 4; ++r)
                    Out[(size_t)(R0 + r) * 512 + C] = acc[mt][nt][r] + bv;
            }
        }
    }
}

// ---------------- flash attention: no max-tracking, no cross-lane main loop ----------------
// S^T = K Q^T (static-max softmax: p = 2^S, exact scale cancel in O/l).
// P^T B-frags = packed in-lane C-regs (V k-slots pre-permuted in gemm0).
// l via ones-MFMA. Zero LDS / zero shuffles in loop. K frags double-buffered in regs.

__device__ __forceinline__ void attn_iter(bf16x8 (&KC)[2][4], bf16x8 (&KN)[2][4],
                                          const bf16x8 (&qf)[4], const bf16x8& onesA,
                                          const fx16& Z,
                                          fx16& O0, fx16& O1, fx16& Lacc,
                                          const u16* __restrict__ Kh,
                                          const u16* __restrict__ Vh,
                                          int lane, int K0) {
    // V^T A-frags for this 64-key block (consumed after exp/pack)
    bf16x8 vf[2][4];
    {
        const u16* vb = Vh + (size_t)(K0 >> 6) * 4096 + lane * 8;
#pragma unroll
        for (int dt = 0; dt < 2; ++dt)
#pragma unroll
            for (int ch = 0; ch < 4; ++ch)
                vf[dt][ch] = ld8(vb + (dt * 4 + ch) * 512);
    }
    // prefetch next iteration's K frags
    {
        int kn0 = (K0 + 64) & 4095;
        const u16* kb = Kh + (size_t)(kn0 >> 5) * 2048 + lane * 8;
#pragma unroll
        for (int dc = 0; dc < 4; ++dc) {
            KN[0][dc] = ld8(kb + dc * 512);
            KN[1][dc] = ld8(kb + 2048 + dc * 512);
        }
    }
    // S^T = K Q^T (C init from persistent zero regs)
    fx16 S0 = Z, S1 = Z;
#pragma unroll
    for (int dc = 0; dc < 4; ++dc) {
        S0 = __builtin_amdgcn_mfma_f32_32x32x16_bf16(KC[0][dc], qf[dc], S0, 0, 0, 0);
        S1 = __builtin_amdgcn_mfma_f32_32x32x16_bf16(KC[1][dc], qf[dc], S1, 0, 0, 0);
    }
    // p = 2^S; packed pairs of consecutive C-regs ARE the B-frags (k-slot permuted V)
    uint32_t pk0[8], pk1[8];
#pragma unroll
    for (int i = 0; i < 8; ++i) {
        pk0[i] = pk2bf(__builtin_amdgcn_exp2f(S0[2 * i]), __builtin_amdgcn_exp2f(S0[2 * i + 1]));
        pk1[i] = pk2bf(__builtin_amdgcn_exp2f(S1[2 * i]), __builtin_amdgcn_exp2f(S1[2 * i + 1]));
    }
    // O^T += V^T P^T ; l += 1^T P^T (ones-MFMA row sums)
#pragma unroll
    for (int c = 0; c < 4; ++c) {
        const uint32_t* pk = (c < 2) ? pk0 : pk1;
        int o = (c & 1) * 4;
        int4 bi; bi.x = (int)pk[o]; bi.y = (int)pk[o + 1]; bi.z = (int)pk[o + 2]; bi.w = (int)pk[o + 3];
        bf16x8 bfrag = __builtin_bit_cast(bf16x8, bi);
        O0 = __builtin_amdgcn_mfma_f32_32x32x16_bf16(vf[0][c], bfrag, O0, 0, 0, 0);
        O1 = __builtin_amdgcn_mfma_f32_32x32x16_bf16(vf[1][c], bfrag, O1, 0, 0, 0);
        Lacc = __builtin_amdgcn_mfma_f32_32x32x16_bf16(onesA, bfrag, Lacc, 0, 0, 0);
    }
}

__global__ __launch_bounds__(256, 2) void attn_kernel(const u16* __restrict__ Qf,
                                                      const u16* __restrict__ Kf,
                                                      const u16* __restrict__ Vf,
                                                      u16* __restrict__ Ob) {
    __shared__ __align__(16) u16 Eo[4 * 32 * 68];

    int tid = threadIdx.x;
    int w = tid >> 6, lane = tid & 63;
    int q32 = lane & 31, h = lane >> 5;
    // XCD swizzle: all 32 q-blocks of one (b,h) land on one XCD
    int bh = ((blockIdx.x & 7) << 1) | ((blockIdx.x >> 3) & 1);
    int qt = blockIdx.x >> 4;
    int q0 = qt * 128;

    const u16* Qh = Qf + (size_t)bh * 262144;
    const u16* Kh = Kf + (size_t)bh * 262144;
    const u16* Vh = Vf + (size_t)bh * 262144;

    bf16x8 qf[4];
    {
        const u16* qb = Qh + (size_t)(qt * 4 + w) * 2048 + lane * 8;
#pragma unroll
        for (int dc = 0; dc < 4; ++dc)
            qf[dc] = ld8(qb + dc * 512);
    }

    int4 oi; oi.x = oi.y = oi.z = oi.w = 0x3F803F80;           // bf16 ones
    const bf16x8 onesA = __builtin_bit_cast(bf16x8, oi);
    const fx16 Z = {};
    fx16 O0 = {}, O1 = {}, Lacc = {};

    bf16x8 kA[2][4], kB[2][4];
    {
        const u16* kb = Kh + lane * 8;
#pragma unroll
        for (int dc = 0; dc < 4; ++dc) {
            kA[0][dc] = ld8(kb + dc * 512);
            kA[1][dc] = ld8(kb + 2048 + dc * 512);
        }
    }

    for (int k0 = 0; k0 < 4096; k0 += 128) {
        // keep the 4 waves lockstep for L1 reuse of shared K/V bytes.
        // raw s_barrier: must NOT emit waitcnt (prefetches stay in flight).
        asm volatile("s_barrier" ::: "memory");
        attn_iter(kA, kB, qf, onesA, Z, O0, O1, Lacc, Kh, Vh, lane, k0);
        attn_iter(kB, kA, qf, onesA, Z, O0, O1, Lacc, Kh, Vh, lane, k0 + 64);
    }

    // epilogue: O^T/l -> LDS transpose -> coalesced global bf16 store
    float inv = 1.0f / Lacc[0];
    int ebase = w * 2176 + q32 * 68;
#pragma unroll
    for (int i = 0; i < 8; ++i) {
        int dbase = 8 * (i >> 1) + (i & 1) * 2 + 4 * h;
        uint32_t p0 = pk2bf(O0[2 * i] * inv, O0[2 * i + 1] * inv);
        uint32_t p1 = pk2bf(O1[2 * i] * inv, O1[2 * i + 1] * inv);
        *(uint32_t*)&Eo[ebase + dbase]      = p0;
        *(uint32_t*)&Eo[ebase + dbase + 32] = p1;
    }
    __syncthreads();
    int row = lane >> 1, half = lane & 1;
    int rb = w * 2176 + row * 68 + half * 32;
    int b = bh >> 3, hh = bh & 7;
    size_t gb = ((size_t)(b * 4096 + q0 + w * 32 + row)) * 512 + hh * 64 + half * 32;
#pragma unroll
    for (int s = 0; s < 4; ++s) {
        uint2 a = *(const uint2*)&Eo[rb + s * 8];
        uint2 c = *(const uint2*)&Eo[rb + s * 8 + 4];
        int4 v; v.x = (int)a.x; v.y = (int)a.y; v.z = (int)c.x; v.w = (int)c.y;
        *(int4*)(Ob + gb + s * 8) = v;
    }
}

// ---------------- launcher ----------------

extern "C" void kernel_launch(void* const* d_in, const int* in_sizes, int n_in,
                              void* d_out, int out_size, void* d_ws, size_t ws_size,
                              hipStream_t stream) {
    const float* x     = (const float*)d_in[0];   // [2,4096,512]
    const float* w_qkv = (const float*)d_in[1];   // [512,1536]
    const float* w_out = (const float*)d_in[2];   // [512,512]
    const float* b_out = (const float*)d_in[3];   // [512]
    float* out = (float*)d_out;                   // [2,4096,512] fp32

    char* ws = (char*)d_ws;
    u16* wqkv_t = (u16*)(ws);                     //  1.5 MB  [1536][512]
    u16* wout_t = (u16*)(ws + 1572864);           //  0.5 MB  [512][512]
    u16* Qfb    = (u16*)(ws + 2097152);           //  8 MB fragment-major (log2-scaled)
    u16* Kfb    = (u16*)(ws + 10485760);          //  8 MB fragment-major
    u16* Vfb    = (u16*)(ws + 18874368);          //  8 MB fragment-major, k-slot permuted
    u16* Ob     = (u16*)(ws + 27262976);          //  8 MB [8192][512]

    transpose_cast_kernel<<<dim3(32, 8), 256, 0, stream>>>(w_qkv, wqkv_t, w_out, wout_t);
    gemm_kernel<0><<<768, 256, 0, stream>>>(x, wqkv_t, Qfb, Kfb, Vfb, nullptr, nullptr, 1536);
    attn_kernel<<<512, 256, 0, stream>>>(Qfb, Kfb, Vfb, Ob);
    gemm_kernel<1><<<256, 256, 0, stream>>>(Ob, wout_t, nullptr, nullptr, nullptr, b_out, out, 512);
}

// Round 7
// 216.467 us; speedup vs baseline: 1.5864x; 1.0169x over previous
//
#include <hip/hip_runtime.h>
#include <stdint.h>

typedef unsigned short u16;
typedef __bf16 bf16x8 __attribute__((ext_vector_type(8)));
typedef float fx4 __attribute__((ext_vector_type(4)));
typedef float fx16 __attribute__((ext_vector_type(16)));

// ---------------- helpers ----------------

__device__ __forceinline__ u16 f2bf(float f) {
    unsigned int u = __float_as_uint(f);
    u += 0x7fffu + ((u >> 16) & 1u);   // RNE
    return (u16)(u >> 16);
}

__device__ __forceinline__ bf16x8 ld8(const u16* p) {
    return __builtin_bit_cast(bf16x8, *(const int4*)p);
}

// pack two fp32 -> packed bf16 dword (round-half-up)
__device__ __forceinline__ uint32_t pk2bf(float lo, float hi) {
    uint32_t a = __float_as_uint(lo) + 0x8000u;
    uint32_t b = __float_as_uint(hi) + 0x8000u;
    return __builtin_amdgcn_perm(b, a, 0x07060302u);
}

// async global->LDS, 16B per lane: HW writes lds_base + lane*16
typedef __attribute__((address_space(3))) uint32_t lds_u32;
typedef __attribute__((address_space(1))) const uint32_t glb_u32;
__device__ __forceinline__ void glds16(const u16* g, u16* l) {
    __builtin_amdgcn_global_load_lds((glb_u32*)g, (lds_u32*)l, 16, 0, 0);
}

// ---------------- kernel 0a: cast x -> bf16 ----------------

__global__ __launch_bounds__(256) void cast_x_kernel(const float* __restrict__ x,
                                                     u16* __restrict__ xb) {
    int idx = blockIdx.x * 256 + threadIdx.x;   // 8 elems per thread
    const float4* p = (const float4*)(x + (size_t)idx * 8);
    float4 a = p[0], b = p[1];
    int4 v;
    v.x = (int)pk2bf(a.x, a.y); v.y = (int)pk2bf(a.z, a.w);
    v.z = (int)pk2bf(b.x, b.y); v.w = (int)pk2bf(b.z, b.w);
    *(int4*)(xb + (size_t)idx * 8) = v;
}

// ---------------- kernel 0b: transpose + cast both weight matrices ----------------
// grid (32, 8): bx<24 -> w_qkv [512][1536], else w_out [512][512]

__global__ __launch_bounds__(256) void transpose_cast_kernel(const float* __restrict__ w_qkv,
                                                             u16* __restrict__ wqkv_t,
                                                             const float* __restrict__ w_out,
                                                             u16* __restrict__ wout_t) {
    __shared__ float T[64][65];
    int t = threadIdx.x;
    int bx = blockIdx.x;
    const float* in; u16* out; int NR = 512, NC;
    if (bx < 24) { in = w_qkv; out = wqkv_t; NC = 1536; }
    else         { in = w_out; out = wout_t; NC = 512; bx -= 24; }
    int i0 = blockIdx.y * 64, j0 = bx * 64;
    int r = t >> 4, cc = t & 15;
#pragma unroll
    for (int j = 0; j < 4; ++j) {
        int row = r + j * 16;
        float4 v = *(const float4*)(in + (size_t)(i0 + row) * NC + j0 + cc * 4);
        T[row][cc * 4 + 0] = v.x; T[row][cc * 4 + 1] = v.y;
        T[row][cc * 4 + 2] = v.z; T[row][cc * 4 + 3] = v.w;
    }
    __syncthreads();
#pragma unroll
    for (int j = 0; j < 4; ++j) {
        int jr = r + j * 16;
        unsigned int u0 = f2bf(T[cc * 4 + 0][jr]) | ((unsigned int)f2bf(T[cc * 4 + 1][jr]) << 16);
        unsigned int u1 = f2bf(T[cc * 4 + 2][jr]) | ((unsigned int)f2bf(T[cc * 4 + 3][jr]) << 16);
        uint2 u; u.x = u0; u.y = u1;
        *(uint2*)(out + (size_t)(j0 + jr) * NR + i0 + cc * 4) = u;
    }
}

// ---------------- GEMM: C[M,Ncols] = A[M,512] * Bt[Ncols,512]^T ----------------
// A bf16; A and B staged via global_load_lds. XCD-aware block swizzle: all ntn
// column-blocks of one row-tile land on one XCD (A-tile fetched once per L2).
// MODE 0: epilogue restages C-tile in LDS in fragment-blob order -> Qf/Kf/Vf.
// MODE 1: -> d_out fp32 + bias.

#define QSCALE 0.180336880f   // (1/8) * log2(e): logits in log2 domain

template<int MODE>
__global__ __launch_bounds__(256) void gemm_kernel(const u16* __restrict__ A,
                                                   const u16* __restrict__ Bt,
                                                   u16* __restrict__ Qf,
                                                   u16* __restrict__ Kf,
                                                   u16* __restrict__ Vf,
                                                   const float* __restrict__ bias,
                                                   float* __restrict__ Out,
                                                   int Ncols) {
    __shared__ __align__(16) u16 Sh[16384];        // As=Sh[0..4096), Bs=Sh[4096..8192); epilogue uses all
    int tid = threadIdx.x;
    int w = tid >> 6, lane = tid & 63;
    int m16 = lane & 15, quad = lane >> 4;
    int ntn = Ncols / 128;
    // XCD swizzle: consecutive blocks (same XCD, round-robin heuristic) share a row-tile
    int g = blockIdx.x;
    int xcd = g & 7, j = g >> 3;
    int by = xcd + 8 * (j / ntn);
    int bx = j % ntn;
    int r0 = by * 128, c0 = bx * 128;
    int wr = w >> 1, wc = w & 1;
    int lrow = lane >> 2, lchk = (lane & 3) * 8;   // glds lane mapping

    fx4 acc[4][4] = {};

    for (int k0 = 0; k0 < 512; k0 += 32) {
        __syncthreads();
#pragma unroll
        for (int jj = 0; jj < 2; ++jj) {
            int rw = jj * 64 + w * 16;             // wave-uniform row base
            glds16(A  + (size_t)(r0 + rw + lrow) * 512 + k0 + lchk, &Sh[rw * 32]);
            glds16(Bt + (size_t)(c0 + rw + lrow) * 512 + k0 + lchk, &Sh[4096 + rw * 32]);
        }
        __syncthreads();
        bf16x8 af[4], bfr[4];
#pragma unroll
        for (int t = 0; t < 4; ++t) {
            af[t]  = ld8(&Sh[(wr * 64 + t * 16 + m16) * 32 + quad * 8]);
            bfr[t] = ld8(&Sh[4096 + (wc * 64 + t * 16 + m16) * 32 + quad * 8]);
        }
#pragma unroll
        for (int mt = 0; mt < 4; ++mt)
#pragma unroll
            for (int nt = 0; nt < 4; ++nt)
                acc[mt][nt] = __builtin_amdgcn_mfma_f32_16x16x32_bf16(af[mt], bfr[nt], acc[mt][nt], 0, 0, 0);
    }

    if (MODE == 0) {
        // ---- epilogue: C-tile -> LDS in fragment-blob order -> coalesced stores ----
        int sec = c0 >> 9;                         // tile-uniform: 0=q 1=k 2=v
        __syncthreads();
        if (sec <= 1) {
            float sc = (sec == 0) ? QSCALE : 1.0f;
#pragma unroll
            for (int mt = 0; mt < 4; ++mt)
#pragma unroll
                for (int nt = 0; nt < 4; ++nt) {
                    int lb = wc * 16 + (wr * 2 + (mt >> 1)) * 4 + nt;
                    int eb = lb * 512 + (m16 >> 3) * 256 + ((mt & 1) * 16 + quad * 4) * 8 + (m16 & 7);
#pragma unroll
                    for (int r = 0; r < 4; ++r)
                        Sh[eb + r * 8] = f2bf(acc[mt][nt][r] * sc);
                }
        } else {
#pragma unroll
            for (int mt = 0; mt < 4; ++mt)
#pragma unroll
                for (int nt = 0; nt < 4; ++nt) {
                    int lb = wc * 16 + wr * 8 + (nt >> 1) * 4 + mt;
                    int eb = lb * 512 + (quad & 1) * 256 + ((nt & 1) * 16 + m16) * 8 + (quad >> 1) * 4;
                    unsigned int u0 = f2bf(acc[mt][nt][0]) | ((unsigned int)f2bf(acc[mt][nt][1]) << 16);
                    unsigned int u1 = f2bf(acc[mt][nt][2]) | ((unsigned int)f2bf(acc[mt][nt][3]) << 16);
                    uint2 u; u.x = u0; u.y = u1;
                    *(uint2*)&Sh[eb] = u;
                }
        }
        __syncthreads();
        int b_ = r0 >> 12, n0 = r0 & 4095, hd0 = (c0 >> 6) & 7;
        u16* dst; size_t gb0;
        if (sec == 0)      { dst = Qf; gb0 = (size_t)(n0 >> 5) * 2048; }
        else if (sec == 1) { dst = Kf; gb0 = (size_t)(n0 >> 5) * 2048; }
        else               { dst = Vf; gb0 = (size_t)(n0 >> 6) * 4096; }
        int hl = tid >> 7;                         // head within tile
        size_t gbase = (size_t)(b_ * 8 + hd0 + hl) * 262144 + gb0 + (size_t)(tid & 127) * 64;
#pragma unroll
        for (int s = 0; s < 8; ++s)
            *(int4*)(dst + gbase + s * 8) = *(const int4*)&Sh[tid * 64 + s * 8];
    } else {
#pragma unroll
        for (int mt = 0; mt < 4; ++mt) {
            int R0 = r0 + wr * 64 + mt * 16 + quad * 4;
#pragma unroll
            for (int nt = 0; nt < 4; ++nt) {
                int C = c0 + wc * 64 + nt * 16 + m16;
                float bv = bias[C];
#pragma unroll
                for (int r = 0; r < 4; ++r)
                    Out[(size_t)(R0 + r) * 512 + C] = acc[mt][nt][r] + bv;
            }
        }
    }
}

// ---------------- flash attention: LDS-staged K, global V, no cross-lane loop ----------------
// Static-max softmax (p = 2^S). P^T B-frags = packed in-lane C-regs (V k-slot permuted).
// K staged via global_load_lds into a 2x8KB double buffer (cuts 4x cross-wave VMEM
// redundancy); prefetch issued a full iter before the barrier so the drain is cheap.

__global__ __launch_bounds__(256, 2) void attn_kernel(const u16* __restrict__ Qf,
                                                      const u16* __restrict__ Kf,
                                                      const u16* __restrict__ Vf,
                                                      u16* __restrict__ Ob) {
    __shared__ __align__(16) u16 Ks[2][4096];      // K frag double buffer (8 KB each)
    __shared__ __align__(16) u16 Eo[4 * 32 * 68];  // epilogue transpose

    int tid = threadIdx.x;
    int w = tid >> 6, lane = tid & 63;
    int q32 = lane & 31, h = lane >> 5;
    // XCD swizzle: all 32 q-blocks of one (b,h) land on one XCD
    int bh = ((blockIdx.x & 7) << 1) | ((blockIdx.x >> 3) & 1);
    int qt = blockIdx.x >> 4;
    int q0 = qt * 128;

    const u16* Qh = Qf + (size_t)bh * 262144;
    const u16* Kh = Kf + (size_t)bh * 262144;
    const u16* Vh = Vf + (size_t)bh * 262144;

    bf16x8 qf[4];
    {
        const u16* qb = Qh + (size_t)(qt * 4 + w) * 2048 + lane * 8;
#pragma unroll
        for (int dc = 0; dc < 4; ++dc)
            qf[dc] = ld8(qb + dc * 512);
    }

    int4 oi; oi.x = oi.y = oi.z = oi.w = 0x3F803F80;           // bf16 ones
    const bf16x8 onesA = __builtin_bit_cast(bf16x8, oi);
    const fx16 Z = {};
    fx16 O0 = {}, O1 = {}, Lacc = {};

    // prologue: stage keys [0,64) into Ks[0] (each wave stages 2 KB)
    glds16(Kh + w * 1024 + lane * 8,       &Ks[0][w * 1024]);
    glds16(Kh + w * 1024 + 512 + lane * 8, &Ks[0][w * 1024 + 512]);
    __syncthreads();

    for (int it = 0; it < 64; ++it) {
        int K0 = it << 6;
        int cur = it & 1, nxt = cur ^ 1;
        // stage next 64-key K block (issued first: full iter body covers its latency)
        {
            int kn = (K0 + 64) & 4095;
            const u16* ks = Kh + (size_t)kn * 64 + w * 1024 + lane * 8;
            glds16(ks,       &Ks[nxt][w * 1024]);
            glds16(ks + 512, &Ks[nxt][w * 1024 + 512]);
        }
        // V^T A-frags from global (consumed after exp/pack)
        bf16x8 vf[2][4];
        {
            const u16* vb = Vh + (size_t)K0 * 64 + lane * 8;
#pragma unroll
            for (int dt = 0; dt < 2; ++dt)
#pragma unroll
                for (int ch = 0; ch < 4; ++ch)
                    vf[dt][ch] = ld8(vb + (dt * 4 + ch) * 512);
        }
        // K frags from LDS
        bf16x8 kf[2][4];
#pragma unroll
        for (int dc = 0; dc < 4; ++dc) {
            kf[0][dc] = ld8(&Ks[cur][dc * 512 + lane * 8]);
            kf[1][dc] = ld8(&Ks[cur][2048 + dc * 512 + lane * 8]);
        }
        // S^T = K Q^T
        fx16 S0 = Z, S1 = Z;
#pragma unroll
        for (int dc = 0; dc < 4; ++dc) {
            S0 = __builtin_amdgcn_mfma_f32_32x32x16_bf16(kf[0][dc], qf[dc], S0, 0, 0, 0);
            S1 = __builtin_amdgcn_mfma_f32_32x32x16_bf16(kf[1][dc], qf[dc], S1, 0, 0, 0);
        }
        // p = 2^S; packed pairs of consecutive C-regs ARE the B-frags
        uint32_t pk0[8], pk1[8];
#pragma unroll
        for (int i = 0; i < 8; ++i) {
            pk0[i] = pk2bf(__builtin_amdgcn_exp2f(S0[2 * i]), __builtin_amdgcn_exp2f(S0[2 * i + 1]));
            pk1[i] = pk2bf(__builtin_amdgcn_exp2f(S1[2 * i]), __builtin_amdgcn_exp2f(S1[2 * i + 1]));
        }
        // O^T += V^T P^T ; l += 1^T P^T
#pragma unroll
        for (int c = 0; c < 4; ++c) {
            const uint32_t* pk = (c < 2) ? pk0 : pk1;
            int o = (c & 1) * 4;
            int4 bi; bi.x = (int)pk[o]; bi.y = (int)pk[o + 1]; bi.z = (int)pk[o + 2]; bi.w = (int)pk[o + 3];
            bf16x8 bfrag = __builtin_bit_cast(bf16x8, bi);
            O0 = __builtin_amdgcn_mfma_f32_32x32x16_bf16(vf[0][c], bfrag, O0, 0, 0, 0);
            O1 = __builtin_amdgcn_mfma_f32_32x32x16_bf16(vf[1][c], bfrag, O1, 0, 0, 0);
            Lacc = __builtin_amdgcn_mfma_f32_32x32x16_bf16(onesA, bfrag, Lacc, 0, 0, 0);
        }
        // barrier: protects Ks[cur] (re-staged next iter) + completes Ks[nxt] staging.
        // vmcnt(0) drain is cheap: newest outstanding loads are ~a full iter old.
        __syncthreads();
    }

    // epilogue: O^T/l -> LDS transpose -> coalesced global bf16 store
    float inv = 1.0f / Lacc[0];
    int ebase = w * 2176 + q32 * 68;
#pragma unroll
    for (int i = 0; i < 8; ++i) {
        int dbase = 8 * (i >> 1) + (i & 1) * 2 + 4 * h;
        uint32_t p0 = pk2bf(O0[2 * i] * inv, O0[2 * i + 1] * inv);
        uint32_t p1 = pk2bf(O1[2 * i] * inv, O1[2 * i + 1] * inv);
        *(uint32_t*)&Eo[ebase + dbase]      = p0;
        *(uint32_t*)&Eo[ebase + dbase + 32] = p1;
    }
    __syncthreads();
    int row = lane >> 1, half = lane & 1;
    int rb = w * 2176 + row * 68 + half * 32;
    int b = bh >> 3, hh = bh & 7;
    size_t gb = ((size_t)(b * 4096 + q0 + w * 32 + row)) * 512 + hh * 64 + half * 32;
#pragma unroll
    for (int s = 0; s < 4; ++s) {
        uint2 a = *(const uint2*)&Eo[rb + s * 8];
        uint2 c = *(const uint2*)&Eo[rb + s * 8 + 4];
        int4 v; v.x = (int)a.x; v.y = (int)a.y; v.z = (int)c.x; v.w = (int)c.y;
        *(int4*)(Ob + gb + s * 8) = v;
    }
}

// ---------------- launcher ----------------

extern "C" void kernel_launch(void* const* d_in, const int* in_sizes, int n_in,
                              void* d_out, int out_size, void* d_ws, size_t ws_size,
                              hipStream_t stream) {
    const float* x     = (const float*)d_in[0];   // [2,4096,512]
    const float* w_qkv = (const float*)d_in[1];   // [512,1536]
    const float* w_out = (const float*)d_in[2];   // [512,512]
    const float* b_out = (const float*)d_in[3];   // [512]
    float* out = (float*)d_out;                   // [2,4096,512] fp32

    char* ws = (char*)d_ws;
    u16* x_b    = (u16*)(ws);                     //  8 MB [8192][512] bf16
    u16* wqkv_t = (u16*)(ws + 8388608);           //  1.5 MB  [1536][512]
    u16* wout_t = (u16*)(ws + 9961472);           //  0.5 MB  [512][512]
    u16* Qfb    = (u16*)(ws + 10485760);          //  8 MB fragment-major (log2-scaled)
    u16* Kfb    = (u16*)(ws + 18874368);          //  8 MB fragment-major
    u16* Vfb    = (u16*)(ws + 27262976);          //  8 MB fragment-major, k-slot permuted
    u16* Ob     = (u16*)(ws + 35651584);          //  8 MB [8192][512]

    cast_x_kernel<<<2048, 256, 0, stream>>>(x, x_b);
    transpose_cast_kernel<<<dim3(32, 8), 256, 0, stream>>>(w_qkv, wqkv_t, w_out, wout_t);
    gemm_kernel<0><<<768, 256, 0, stream>>>(x_b, wqkv_t, Qfb, Kfb, Vfb, nullptr, nullptr, 1536);
    attn_kernel<<<512, 256, 0, stream>>>(Qfb, Kfb, Vfb, Ob);
    gemm_kernel<1><<<256, 256, 0, stream>>>(Ob, wout_t, nullptr, nullptr, nullptr, b_out, out, 512);
}